// Round 5
// baseline (122.310 us; speedup 1.0000x reference)
//
#include <hip/hip_runtime.h>
#include <math.h>

// Geometry (fixed by the reference)
#define Rdim 513                 // IN_DIM + 1 bias row
#define MSTRIDE ((size_t)512 * Rdim)   // E element stride for m -> m+1 at fixed c

// Native clang vector type (accepted by __builtin_nontemporal_load)
typedef float v4f __attribute__((ext_vector_type(4)));

// 4B-aligned float4 proxy for the (possibly) misaligned x-window loads
struct f4a { float x, y, z, w; };

// One wave owns ONE column c for 16 samples m0..m0+15.
//  - mu[c,:] and sigma[c,:]=sqrt(var[c,:]) live in registers for the whole wave.
//  - Per iteration: load E row (2 aligned nontemporal float4 + <=1 scalar) and
//    the x-hat window for sample m (2 f4a + <=1 scalar; L1-resident since all
//    8 waves of the block read the same x row in the same iteration).
//  - Alignment: E row element base = (m*512+c)*513 == c (mod 4); pad=(4-c%4)&3
//    makes every float4 in the window [pad, pad+4*CH) 16B-aligned.
//  - Reduction: 16 per-lane partials v[k], merged butterfly (offsets 1,2,4,8
//    halving + 16,32 full) -> lane L ends with row (L&15)'s total. 17 shuffles
//    for 16 rows instead of 96.
__global__ __launch_bounds__(512) void bnn_kernel(const float* __restrict__ x,
                                                  const float* __restrict__ mu,
                                                  const float* __restrict__ var,
                                                  const float* __restrict__ E,
                                                  float* __restrict__ out) {
    const int lane = threadIdx.x & 63;
    const int w    = threadIdx.x >> 6;       // 0..7
    const int mg   = blockIdx.x >> 6;        // 0..15  (16 m-groups of 16)
    const int cg   = blockIdx.x & 63;        // 0..63  (64 c-groups of 8)
    const int c    = cg * 8 + w;             // fixed column for this wave
    const int m0   = mg * 16;

    const int pad = (4 - (c & 3)) & 3;
    const int CH  = pad ? 127 : 128;         // float4 chunks in aligned window
    const int eA  = pad + 4 * lane;
    const int eB  = pad + 4 * (CH - 64 + lane);

    const size_t crow = (size_t)c * Rdim;
    // Wave-resident mu / sigma windows (aligned; base == 0 mod 4 elems)
    const v4f muA = *(const v4f*)(mu + crow + eA);
    const v4f muB = *(const v4f*)(mu + crow + eB);
    const v4f vA  = *(const v4f*)(var + crow + eA);
    const v4f vB  = *(const v4f*)(var + crow + eB);
    v4f sgA, sgB;
    sgA.x = sqrtf(vA.x); sgA.y = sqrtf(vA.y); sgA.z = sqrtf(vA.z); sgA.w = sqrtf(vA.w);
    sgB.x = sqrtf(vB.x); sgB.y = sqrtf(vB.y); sgB.z = sqrtf(vB.z); sgB.w = sqrtf(vB.w);

    // Scalar leftovers: leading [0,pad) + tail [pad+4CH, 513) incl. bias r=512
    const int nS = pad ? 5 : 1;
    int se = -1;
    if (lane < nS) se = (lane < pad) ? lane : (pad + 4 * CH + (lane - pad));
    float mus = 0.f, sgs = 0.f;
    if (se >= 0) { mus = mu[crow + se]; sgs = sqrtf(var[crow + se]); }
    // pad!=0: lane63's A-chunk == lane0's B-chunk (both chunk 63) -> zero dup via x
    const bool killB = (pad != 0) && (lane == 0);

    size_t eb = ((size_t)m0 * 512 + c) * (size_t)Rdim;   // E row base, m = m0
    const float* xr = x + (size_t)m0 * 512;

    // Prologue: loads for k = 0
    v4f cEa = __builtin_nontemporal_load((const v4f*)(E + eb + eA));
    v4f cEb = __builtin_nontemporal_load((const v4f*)(E + eb + eB));
    f4a cXa = *(const f4a*)(xr + eA);
    f4a cXb = *(const f4a*)(xr + eB);
    float cEs = 0.f, cXs = 0.f;
    if (se >= 0) {
        cEs = __builtin_nontemporal_load(E + eb + se);
        cXs = (se == 512) ? 1.0f : xr[se];
    }
    if (killB) { cXb.x = cXb.y = cXb.z = cXb.w = 0.f; }

    float v[16];
#pragma unroll
    for (int k = 0; k < 16; ++k) {
        // depth-1 prefetch of next sample's E row + x-hat window
        v4f nEa, nEb; f4a nXa, nXb; float nEs = 0.f, nXs = 0.f;
        if (k < 15) {
            const float* Er2 = E + eb + MSTRIDE;
            const float* xr2 = xr + 512;
            nEa = __builtin_nontemporal_load((const v4f*)(Er2 + eA));
            nEb = __builtin_nontemporal_load((const v4f*)(Er2 + eB));
            nXa = *(const f4a*)(xr2 + eA);
            nXb = *(const f4a*)(xr2 + eB);
            if (se >= 0) {
                nEs = __builtin_nontemporal_load(Er2 + se);
                nXs = (se == 512) ? 1.0f : xr2[se];
            }
            if (killB) { nXb.x = nXb.y = nXb.z = nXb.w = 0.f; }
        }

        // v[k] = sum over window of x * (mu + sigma*E)
        float acc;
        acc =             cXa.x * fmaf(sgA.x, cEa.x, muA.x);
        acc = fmaf(cXa.y, fmaf(sgA.y, cEa.y, muA.y), acc);
        acc = fmaf(cXa.z, fmaf(sgA.z, cEa.z, muA.z), acc);
        acc = fmaf(cXa.w, fmaf(sgA.w, cEa.w, muA.w), acc);
        acc = fmaf(cXb.x, fmaf(sgB.x, cEb.x, muB.x), acc);
        acc = fmaf(cXb.y, fmaf(sgB.y, cEb.y, muB.y), acc);
        acc = fmaf(cXb.z, fmaf(sgB.z, cEb.z, muB.z), acc);
        acc = fmaf(cXb.w, fmaf(sgB.w, cEb.w, muB.w), acc);
        acc = fmaf(cXs,  fmaf(sgs, cEs, mus), acc);     // leftovers (0 on idle lanes)
        v[k] = acc;

        if (k < 15) {
            cEa = nEa; cEb = nEb; cXa = nXa; cXb = nXb; cEs = nEs; cXs = nXs;
            eb += MSTRIDE;
            xr += 512;
        }
    }

    // Merged butterfly reduction: 16 values x 64 lanes -> lane L holds row L&15.
    // Each halving stage: keep own-row half, swap the other, one shuffle+add.
#pragma unroll
    for (int j = 0; j < 8; ++j) {
        float a = v[2 * j], b = v[2 * j + 1];
        float keep = (lane & 1) ? b : a;
        float send = (lane & 1) ? a : b;
        v[j] = keep + __shfl_xor(send, 1, 64);
    }
#pragma unroll
    for (int j = 0; j < 4; ++j) {
        float a = v[2 * j], b = v[2 * j + 1];
        float keep = (lane & 2) ? b : a;
        float send = (lane & 2) ? a : b;
        v[j] = keep + __shfl_xor(send, 2, 64);
    }
#pragma unroll
    for (int j = 0; j < 2; ++j) {
        float a = v[2 * j], b = v[2 * j + 1];
        float keep = (lane & 4) ? b : a;
        float send = (lane & 4) ? a : b;
        v[j] = keep + __shfl_xor(send, 4, 64);
    }
    {
        float a = v[0], b = v[1];
        float keep = (lane & 8) ? b : a;
        float send = (lane & 8) ? a : b;
        v[0] = keep + __shfl_xor(send, 8, 64);
    }
    v[0] += __shfl_xor(v[0], 16, 64);
    v[0] += __shfl_xor(v[0], 32, 64);

    if (lane < 16) out[(size_t)(m0 + lane) * 512 + c] = v[0];
}

extern "C" void kernel_launch(void* const* d_in, const int* in_sizes, int n_in,
                              void* d_out, int out_size, void* d_ws, size_t ws_size,
                              hipStream_t stream) {
    const float* x   = (const float*)d_in[0];
    const float* mu  = (const float*)d_in[1];
    const float* var = (const float*)d_in[2];
    const float* E   = (const float*)d_in[3];
    float* out = (float*)d_out;
    // 1024 blocks x 512 threads: 16 m-groups x 64 c-groups, 8 waves (= 8 c) each
    bnn_kernel<<<1024, 512, 0, stream>>>(x, mu, var, E, out);
}

// Round 6
// 106.875 us; speedup vs baseline: 1.1444x; 1.1444x over previous
//
#include <hip/hip_runtime.h>
#include <math.h>

// Geometry (fixed by the reference)
#define Rdim 513            // IN_DIM + 1 bias row
#define SIGMA_ELEMS (512 * Rdim)   // 262656

typedef float v4f __attribute__((ext_vector_type(4)));

__global__ __launch_bounds__(256) void sigma_kernel(const float* __restrict__ var,
                                                    float* __restrict__ sigma, int n) {
    int i = blockIdx.x * 256 + threadIdx.x;
    if (i < n) sigma[i] = sqrtf(var[i]);
}

// R3 structure (proven 61.7us): block b -> (m = b>>3, j = b&7); wave q owns
// rows c = j*64 + q + 4k, k=0..15 (c mod 4 == q fixed -> pad is wave-constant,
// all E/mu/sigma float4s 16B-aligned; block streams 64 consecutive E rows).
// New in R6:
//  - merged butterfly reduction: 16 per-lane partials v[k], 4 halving stages
//    (xor 1,2,4,8) + 2 full butterflies (16,32) = 17 cross-lane ops per 16
//    rows instead of 96 serial ones. Lane L ends with row (L&15)'s total.
//  - nontemporal loads on the E stream (read-once; keep mu/sigma L2-resident).
template <bool USE_SIGMA>
__global__ __launch_bounds__(256) void bnn_kernel(const float* __restrict__ x,
                                                  const float* __restrict__ mu,
                                                  const float* __restrict__ sg,  // sigma (or var)
                                                  const float* __restrict__ E,
                                                  float* __restrict__ out) {
    const int lane = threadIdx.x & 63;
    const int q    = threadIdx.x >> 6;      // wave id == c mod 4
    const int b    = blockIdx.x;            // 2048 blocks
    const int m    = b >> 3;
    const int j    = b & 7;

    const int pad  = (4 - q) & 3;
    const int CH   = pad ? 127 : 128;       // float4 chunks in the aligned window
    const int eA   = pad + 4 * lane;
    const int eB   = pad + 4 * (CH - 64 + lane);

    // x_hat window in registers (window stays < 512; row m fixed for the wave)
    const float* __restrict__ xr = x + m * 512;
    float xA0 = xr[eA], xA1 = xr[eA + 1], xA2 = xr[eA + 2], xA3 = xr[eA + 3];
    float xB0 = xr[eB], xB1 = xr[eB + 1], xB2 = xr[eB + 2], xB3 = xr[eB + 3];
    if (pad && lane == 0) { xB0 = xB1 = xB2 = xB3 = 0.f; }  // dup chunk kill

    // Scalar leftovers: leading [0,pad) + tail [pad+4CH, 513) incl. bias r=512
    const int nS = pad ? 5 : 1;
    int se = -1;
    if (lane < nS) se = (lane < pad) ? lane : (pad + 4 * CH + (lane - pad));
    const float xs = (se >= 0) ? ((se < 512) ? xr[se] : 1.0f) : 0.0f;

    const int c0 = j * 64 + q;              // first c; advances by 4
    size_t eb = ((size_t)m * 512 + c0) * (size_t)Rdim;  // E row element base
    size_t cb = (size_t)c0 * (size_t)Rdim;              // mu/sigma row base

    // Prologue: loads for k = 0
    v4f cEa = __builtin_nontemporal_load((const v4f*)(E + eb + eA));
    v4f cEb = __builtin_nontemporal_load((const v4f*)(E + eb + eB));
    v4f cSa = *(const v4f*)(sg + cb + eA);
    v4f cSb = *(const v4f*)(sg + cb + eB);
    v4f cMa = *(const v4f*)(mu + cb + eA);
    v4f cMb = *(const v4f*)(mu + cb + eB);
    float cEs = 0.f, cSs = 0.f, cMs = 0.f;
    if (se >= 0) {
        cEs = __builtin_nontemporal_load(E + eb + se);
        cSs = sg[cb + se];
        cMs = mu[cb + se];
    }

    float v[16];
#pragma unroll
    for (int k = 0; k < 16; ++k) {
        // depth-1 prefetch of next row (c+4): counted vmcnt, overlaps compute
        v4f nEa, nEb, nSa, nSb, nMa, nMb;
        float nEs = 0.f, nSs = 0.f, nMs = 0.f;
        if (k < 15) {
            const size_t eb2 = eb + 4 * (size_t)Rdim;
            const size_t cb2 = cb + 4 * (size_t)Rdim;
            nEa = __builtin_nontemporal_load((const v4f*)(E + eb2 + eA));
            nEb = __builtin_nontemporal_load((const v4f*)(E + eb2 + eB));
            nSa = *(const v4f*)(sg + cb2 + eA);
            nSb = *(const v4f*)(sg + cb2 + eB);
            nMa = *(const v4f*)(mu + cb2 + eA);
            nMb = *(const v4f*)(mu + cb2 + eB);
            if (se >= 0) {
                nEs = __builtin_nontemporal_load(E + eb2 + se);
                nSs = sg[cb2 + se];
                nMs = mu[cb2 + se];
            }
        }

        // compute current row partial
        v4f sa = cSa, sb = cSb;
        float ss = cSs;
        if (!USE_SIGMA) {
            sa.x = sqrtf(sa.x); sa.y = sqrtf(sa.y); sa.z = sqrtf(sa.z); sa.w = sqrtf(sa.w);
            sb.x = sqrtf(sb.x); sb.y = sqrtf(sb.y); sb.z = sqrtf(sb.z); sb.w = sqrtf(sb.w);
            ss = sqrtf(ss);
        }
        float acc;
        acc =            xA0 * fmaf(sa.x, cEa.x, cMa.x);
        acc = fmaf(xA1, fmaf(sa.y, cEa.y, cMa.y), acc);
        acc = fmaf(xA2, fmaf(sa.z, cEa.z, cMa.z), acc);
        acc = fmaf(xA3, fmaf(sa.w, cEa.w, cMa.w), acc);
        acc = fmaf(xB0, fmaf(sb.x, cEb.x, cMb.x), acc);
        acc = fmaf(xB1, fmaf(sb.y, cEb.y, cMb.y), acc);
        acc = fmaf(xB2, fmaf(sb.z, cEb.z, cMb.z), acc);
        acc = fmaf(xB3, fmaf(sb.w, cEb.w, cMb.w), acc);
        acc = fmaf(xs,  fmaf(ss, cEs, cMs), acc);   // leftovers (xs==0 on idle lanes)
        v[k] = acc;

        if (k < 15) {
            cEa = nEa; cEb = nEb; cSa = nSa; cSb = nSb; cMa = nMa; cMb = nMb;
            cEs = nEs; cSs = nSs; cMs = nMs;
            eb += 4 * (size_t)Rdim;
            cb += 4 * (size_t)Rdim;
        }
    }

    // Merged butterfly: lane L ends with the full 64-lane sum of row (L&15).
#pragma unroll
    for (int jj = 0; jj < 8; ++jj) {
        float a = v[2 * jj], bq = v[2 * jj + 1];
        float keep = (lane & 1) ? bq : a;
        float send = (lane & 1) ? a : bq;
        v[jj] = keep + __shfl_xor(send, 1, 64);
    }
#pragma unroll
    for (int jj = 0; jj < 4; ++jj) {
        float a = v[2 * jj], bq = v[2 * jj + 1];
        float keep = (lane & 2) ? bq : a;
        float send = (lane & 2) ? a : bq;
        v[jj] = keep + __shfl_xor(send, 2, 64);
    }
#pragma unroll
    for (int jj = 0; jj < 2; ++jj) {
        float a = v[2 * jj], bq = v[2 * jj + 1];
        float keep = (lane & 4) ? bq : a;
        float send = (lane & 4) ? a : bq;
        v[jj] = keep + __shfl_xor(send, 4, 64);
    }
    {
        float a = v[0], bq = v[1];
        float keep = (lane & 8) ? bq : a;
        float send = (lane & 8) ? a : bq;
        v[0] = keep + __shfl_xor(send, 8, 64);
    }
    v[0] += __shfl_xor(v[0], 16, 64);
    v[0] += __shfl_xor(v[0], 32, 64);

    // lane L < 16 holds row c = c0 + 4L  ->  out[m*512 + c0 + 4*lane]
    if (lane < 16) out[(size_t)m * 512 + c0 + 4 * lane] = v[0];
}

extern "C" void kernel_launch(void* const* d_in, const int* in_sizes, int n_in,
                              void* d_out, int out_size, void* d_ws, size_t ws_size,
                              hipStream_t stream) {
    const float* x   = (const float*)d_in[0];
    const float* mu  = (const float*)d_in[1];
    const float* var = (const float*)d_in[2];
    const float* E   = (const float*)d_in[3];
    float* out = (float*)d_out;

    const size_t sigma_bytes = (size_t)SIGMA_ELEMS * sizeof(float);
    if (ws_size >= sigma_bytes) {
        float* sigma = (float*)d_ws;
        sigma_kernel<<<(SIGMA_ELEMS + 255) / 256, 256, 0, stream>>>(var, sigma, SIGMA_ELEMS);
        bnn_kernel<true><<<2048, 256, 0, stream>>>(x, mu, sigma, E, out);
    } else {
        bnn_kernel<false><<<2048, 256, 0, stream>>>(x, mu, var, E, out);
    }
}

// Round 7
// 61.825 us; speedup vs baseline: 1.9783x; 1.7287x over previous
//
#include <hip/hip_runtime.h>
#include <math.h>

// Geometry (fixed by the reference)
#define Rdim 513                   // IN_DIM + 1 bias row
#define SIGMA_ELEMS (512 * Rdim)   // 262656

typedef float v4f __attribute__((ext_vector_type(4)));

__global__ __launch_bounds__(256) void sigma_kernel(const float* __restrict__ var,
                                                    float* __restrict__ sigma, int n) {
    int i = blockIdx.x * 256 + threadIdx.x;
    if (i < n) sigma[i] = sqrtf(var[i]);
}

// ONE wave = ONE (m,c) row. 131072 waves total -> ~8 resident waves/SIMD
// (tiny VGPR footprint), so HBM latency is hidden by TLP instead of by
// software pipelining. Per-row math identical to the proven R3 kernel:
//   pad = (4 - c%4)&3 makes every E/sigma/mu float4 in the window
//   [pad, pad+4*CH) 16B-aligned (row*513 == c mod 4); scalar leftovers
//   (leading pad + tail incl. bias r=512) go to lanes 0..4; for pad!=0 the
//   duplicated chunk 63 is killed via x=0 on lane 0's B-chunk.
__global__ __launch_bounds__(256) void bnn_kernel(const float* __restrict__ x,
                                                  const float* __restrict__ mu,
                                                  const float* __restrict__ sg,  // sqrt(var)
                                                  const float* __restrict__ E,
                                                  float* __restrict__ out) {
    const int lane = threadIdx.x & 63;
    const int wid  = threadIdx.x >> 6;                 // 0..3
    const int row  = blockIdx.x * 4 + wid;             // (m,c) pair, 0..131071
    const int m    = row >> 9;
    const int c    = row & 511;

    const int q    = c & 3;
    const int pad  = (4 - q) & 3;
    const int CH   = pad ? 127 : 128;                  // aligned float4 chunks
    const int eA   = pad + 4 * lane;
    const int eB   = pad + 4 * (CH - 64 + lane);

    const size_t eb = (size_t)row * (size_t)Rdim;      // E row element base
    const size_t cb = (size_t)c   * (size_t)Rdim;      // mu/sigma row base
    const float* __restrict__ xr = x + m * 512;

    // x window (scalar loads, L1-shared by the block's 4 waves)
    float xA0 = xr[eA], xA1 = xr[eA + 1], xA2 = xr[eA + 2], xA3 = xr[eA + 3];
    float xB0 = xr[eB], xB1 = xr[eB + 1], xB2 = xr[eB + 2], xB3 = xr[eB + 3];
    if (pad && lane == 0) { xB0 = xB1 = xB2 = xB3 = 0.f; }   // dup-chunk kill

    // Scalar leftovers: leading [0,pad) + tail [pad+4CH, 513) incl. bias 512
    const int nS = pad ? 5 : 1;
    int se = -1;
    if (lane < nS) se = (lane < pad) ? lane : (pad + 4 * CH + (lane - pad));
    const float xs = (se >= 0) ? ((se < 512) ? xr[se] : 1.0f) : 0.0f;

    // All vector loads 16B-aligned by construction
    const v4f Ea = *(const v4f*)(E  + eb + eA);
    const v4f Eb = *(const v4f*)(E  + eb + eB);
    const v4f Sa = *(const v4f*)(sg + cb + eA);
    const v4f Sb = *(const v4f*)(sg + cb + eB);
    const v4f Ma = *(const v4f*)(mu + cb + eA);
    const v4f Mb = *(const v4f*)(mu + cb + eB);
    float Es = 0.f, Ss = 0.f, Ms = 0.f;
    if (se >= 0) { Es = E[eb + se]; Ss = sg[cb + se]; Ms = mu[cb + se]; }

    // acc = sum over window of x * (mu + sigma*E)
    float acc;
    acc =            xA0 * fmaf(Sa.x, Ea.x, Ma.x);
    acc = fmaf(xA1, fmaf(Sa.y, Ea.y, Ma.y), acc);
    acc = fmaf(xA2, fmaf(Sa.z, Ea.z, Ma.z), acc);
    acc = fmaf(xA3, fmaf(Sa.w, Ea.w, Ma.w), acc);
    acc = fmaf(xB0, fmaf(Sb.x, Eb.x, Mb.x), acc);
    acc = fmaf(xB1, fmaf(Sb.y, Eb.y, Mb.y), acc);
    acc = fmaf(xB2, fmaf(Sb.z, Eb.z, Mb.z), acc);
    acc = fmaf(xB3, fmaf(Sb.w, Eb.w, Mb.w), acc);
    acc = fmaf(xs,  fmaf(Ss, Es, Ms), acc);            // leftovers (xs==0 idle)

    // 64-lane sum
#pragma unroll
    for (int off = 32; off >= 1; off >>= 1)
        acc += __shfl_xor(acc, off, 64);

    if (lane == 0) out[row] = acc;
}

extern "C" void kernel_launch(void* const* d_in, const int* in_sizes, int n_in,
                              void* d_out, int out_size, void* d_ws, size_t ws_size,
                              hipStream_t stream) {
    const float* x   = (const float*)d_in[0];
    const float* mu  = (const float*)d_in[1];
    const float* var = (const float*)d_in[2];
    const float* E   = (const float*)d_in[3];
    float* out = (float*)d_out;

    const size_t sigma_bytes = (size_t)SIGMA_ELEMS * sizeof(float);
    if (ws_size >= sigma_bytes) {
        float* sigma = (float*)d_ws;
        sigma_kernel<<<(SIGMA_ELEMS + 255) / 256, 256, 0, stream>>>(var, sigma, SIGMA_ELEMS);
        bnn_kernel<<<32768, 256, 0, stream>>>(x, mu, sigma, E, out);
    } else {
        // Fallback: reuse var pointer, take sqrt inline would change math; ws
        // is always >= 1MB in this harness, but keep a correct fallback:
        sigma_kernel<<<(SIGMA_ELEMS + 255) / 256, 256, 0, stream>>>(var, (float*)d_ws, SIGMA_ELEMS);
        bnn_kernel<<<32768, 256, 0, stream>>>(x, mu, (float*)d_ws, E, out);
    }
}

// Round 8
// 51.975 us; speedup vs baseline: 2.3533x; 1.1895x over previous
//
#include <hip/hip_runtime.h>
#include <math.h>
#include <stdint.h>

// Geometry (fixed by the reference)
#define Rdim 513                   // IN_DIM + 1 bias row
#define SM_ELEMS (512 * Rdim)      // 262656 packed (sigma,mu) pairs

typedef float v4f  __attribute__((ext_vector_type(4)));
typedef uint32_t v4u __attribute__((ext_vector_type(4)));

// round-to-nearest-even fp32 -> bf16 (returned in low 16 bits)
__device__ __forceinline__ uint32_t rne_bf16(float x) {
    uint32_t u = __float_as_uint(x);
    return (u + 0x7FFFu + ((u >> 16) & 1u)) >> 16;
}

// Pack sigma=sqrt(var) into low half, mu into high half of one u32 per (c,r).
__global__ __launch_bounds__(256) void pack_sm_kernel(const float* __restrict__ var,
                                                      const float* __restrict__ mu,
                                                      uint32_t* __restrict__ sm, int n) {
    int i = blockIdx.x * 256 + threadIdx.x;
    if (i < n) {
        uint32_t sb = rne_bf16(sqrtf(var[i]));
        uint32_t mb = rne_bf16(mu[i]);
        sm[i] = (mb << 16) | sb;
    }
}

__device__ __forceinline__ float bf_mu(uint32_t u) { return __uint_as_float(u & 0xFFFF0000u); }
__device__ __forceinline__ float bf_sg(uint32_t u) { return __uint_as_float(u << 16); }

// ONE wave = ONE (m,c) row (proven R7 structure, 61.8us). Changes in R8:
// sigma+mu come from the packed bf16 table SM (2 dwordx4 per row instead of
// 4; 2KB instead of 4KB through L1/L2). E path untouched.
// Alignment: element/pair window [pad, pad+4*CH) is 16B-aligned for both E
// (float) and SM (u32 pair) since row byte base == 4*(c&3) mod 16 for both.
__global__ __launch_bounds__(256) void bnn_kernel(const float* __restrict__ x,
                                                  const uint32_t* __restrict__ SM,
                                                  const float* __restrict__ E,
                                                  float* __restrict__ out) {
    const int lane = threadIdx.x & 63;
    const int wid  = threadIdx.x >> 6;                 // 0..3
    const int row  = blockIdx.x * 4 + wid;             // (m,c) pair, 0..131071
    const int m    = row >> 9;
    const int c    = row & 511;

    const int q    = c & 3;
    const int pad  = (4 - q) & 3;
    const int CH   = pad ? 127 : 128;                  // aligned 16B chunks
    const int eA   = pad + 4 * lane;
    const int eB   = pad + 4 * (CH - 64 + lane);

    const size_t eb = (size_t)row * (size_t)Rdim;      // E row element base
    const size_t cb = (size_t)c   * (size_t)Rdim;      // SM row pair base
    const float* __restrict__ xr = x + m * 512;

    // x window (L1-shared by the block's 4 waves)
    float xA0 = xr[eA], xA1 = xr[eA + 1], xA2 = xr[eA + 2], xA3 = xr[eA + 3];
    float xB0 = xr[eB], xB1 = xr[eB + 1], xB2 = xr[eB + 2], xB3 = xr[eB + 3];
    if (pad && lane == 0) { xB0 = xB1 = xB2 = xB3 = 0.f; }   // dup-chunk kill

    // Scalar leftovers: leading [0,pad) + tail [pad+4CH, 513) incl. bias 512
    const int nS = pad ? 5 : 1;
    int se = -1;
    if (lane < nS) se = (lane < pad) ? lane : (pad + 4 * CH + (lane - pad));
    const float xs = (se >= 0) ? ((se < 512) ? xr[se] : 1.0f) : 0.0f;

    // Vector loads: 16B-aligned by construction
    const v4f Ea = *(const v4f*)(E  + eb + eA);
    const v4f Eb = *(const v4f*)(E  + eb + eB);
    const v4u Pa = *(const v4u*)(SM + cb + eA);
    const v4u Pb = *(const v4u*)(SM + cb + eB);
    float Es = 0.f, xs_mu = 0.f, xs_sg = 0.f;
    if (se >= 0) {
        Es = E[eb + se];
        uint32_t Ps = SM[cb + se];
        xs_mu = bf_mu(Ps); xs_sg = bf_sg(Ps);
    }

    // acc = sum over window of x * (mu + sigma*E)
    float acc;
    acc =            xA0 * fmaf(bf_sg(Pa.x), Ea.x, bf_mu(Pa.x));
    acc = fmaf(xA1, fmaf(bf_sg(Pa.y), Ea.y, bf_mu(Pa.y)), acc);
    acc = fmaf(xA2, fmaf(bf_sg(Pa.z), Ea.z, bf_mu(Pa.z)), acc);
    acc = fmaf(xA3, fmaf(bf_sg(Pa.w), Ea.w, bf_mu(Pa.w)), acc);
    acc = fmaf(xB0, fmaf(bf_sg(Pb.x), Eb.x, bf_mu(Pb.x)), acc);
    acc = fmaf(xB1, fmaf(bf_sg(Pb.y), Eb.y, bf_mu(Pb.y)), acc);
    acc = fmaf(xB2, fmaf(bf_sg(Pb.z), Eb.z, bf_mu(Pb.z)), acc);
    acc = fmaf(xB3, fmaf(bf_sg(Pb.w), Eb.w, bf_mu(Pb.w)), acc);
    acc = fmaf(xs,  fmaf(xs_sg, Es, xs_mu), acc);      // leftovers (xs==0 idle)

    // 64-lane sum
#pragma unroll
    for (int off = 32; off >= 1; off >>= 1)
        acc += __shfl_xor(acc, off, 64);

    if (lane == 0) out[row] = acc;
}

extern "C" void kernel_launch(void* const* d_in, const int* in_sizes, int n_in,
                              void* d_out, int out_size, void* d_ws, size_t ws_size,
                              hipStream_t stream) {
    const float* x   = (const float*)d_in[0];
    const float* mu  = (const float*)d_in[1];
    const float* var = (const float*)d_in[2];
    const float* E   = (const float*)d_in[3];
    float* out = (float*)d_out;

    uint32_t* SM = (uint32_t*)d_ws;   // 1.05 MB; ws is ~1 GB in this harness
    pack_sm_kernel<<<(SM_ELEMS + 255) / 256, 256, 0, stream>>>(var, mu, SM, SM_ELEMS);
    bnn_kernel<<<32768, 256, 0, stream>>>(x, SM, E, out);
}

// Round 9
// 51.077 us; speedup vs baseline: 2.3946x; 1.0176x over previous
//
#include <hip/hip_runtime.h>
#include <math.h>
#include <stdint.h>

// Geometry (fixed by the reference)
#define Rdim 513                   // IN_DIM + 1 bias row
#define SM_ELEMS (512 * Rdim)      // 262656 packed (sigma,mu) pairs

typedef float v4f  __attribute__((ext_vector_type(4)));
typedef uint32_t v4u __attribute__((ext_vector_type(4)));

// round-to-nearest-even fp32 -> bf16 (low 16 bits)
__device__ __forceinline__ uint32_t rne_bf16(float x) {
    uint32_t u = __float_as_uint(x);
    return (u + 0x7FFFu + ((u >> 16) & 1u)) >> 16;
}

// SM[c,r] = (bf16(mu) << 16) | bf16(sqrt(var))
__global__ __launch_bounds__(256) void pack_sm_kernel(const float* __restrict__ var,
                                                      const float* __restrict__ mu,
                                                      uint32_t* __restrict__ sm, int n) {
    int i = blockIdx.x * 256 + threadIdx.x;
    if (i < n) {
        uint32_t sb = rne_bf16(sqrtf(var[i]));
        uint32_t mb = rne_bf16(mu[i]);
        sm[i] = (mb << 16) | sb;
    }
}

__device__ __forceinline__ float bf_mu(uint32_t u) { return __uint_as_float(u & 0xFFFF0000u); }
__device__ __forceinline__ float bf_sg(uint32_t u) { return __uint_as_float(u << 16); }

// ONE wave = TWO rows (m0,c) and (m0+1,c): SM row c loaded ONCE for both.
// Block b: mg=b>>7 (m0=2*mg), cg=b&127; wave w: c=cg*4+w.
//   - E sweep stays sequential: an mg-stripe's 128 blocks cover two contiguous
//     1.05MB E regions; consecutive blocks advance c by 4 (adjacent rows).
//   - pad=(4-c%4)&3 (m*512 == 0 mod 4) -> all E/SM dwordx4 16B-aligned.
//   - Merged reduction: pairing stage (xor 1) + butterflies 2,4,8,16,32 ->
//     even lanes hold row m0's sum, odd lanes row m1's. 6 shuffles / 2 rows.
__global__ __launch_bounds__(256) void bnn_kernel(const float* __restrict__ x,
                                                  const uint32_t* __restrict__ SM,
                                                  const float* __restrict__ E,
                                                  float* __restrict__ out) {
    const int lane = threadIdx.x & 63;
    const int w    = threadIdx.x >> 6;                 // 0..3
    const int b    = blockIdx.x;                       // 0..16383
    const int mg   = b >> 7;                           // 0..127
    const int cg   = b & 127;                          // 0..127
    const int c    = cg * 4 + w;
    const int m0   = mg * 2;

    const int q    = c & 3;
    const int pad  = (4 - q) & 3;
    const int CH   = pad ? 127 : 128;                  // aligned 16B chunks
    const int eA   = pad + 4 * lane;
    const int eB   = pad + 4 * (CH - 64 + lane);

    const size_t row0 = (size_t)m0 * 512 + c;
    const size_t eb0  = row0 * (size_t)Rdim;           // E row m0
    const size_t eb1  = eb0 + (size_t)512 * Rdim;      // E row m0+1
    const size_t cb   = (size_t)c * (size_t)Rdim;      // SM row
    const float* __restrict__ xr0 = x + m0 * 512;
    const float* __restrict__ xr1 = xr0 + 512;

    // ---- issue all vector loads upfront ----
    const v4u Pa  = *(const v4u*)(SM + cb + eA);
    const v4u Pb  = *(const v4u*)(SM + cb + eB);
    const v4f E0a = *(const v4f*)(E + eb0 + eA);
    const v4f E0b = *(const v4f*)(E + eb0 + eB);
    const v4f E1a = *(const v4f*)(E + eb1 + eA);
    const v4f E1b = *(const v4f*)(E + eb1 + eB);

    // x windows (L1-resident)
    float x0A0 = xr0[eA], x0A1 = xr0[eA+1], x0A2 = xr0[eA+2], x0A3 = xr0[eA+3];
    float x0B0 = xr0[eB], x0B1 = xr0[eB+1], x0B2 = xr0[eB+2], x0B3 = xr0[eB+3];
    float x1A0 = xr1[eA], x1A1 = xr1[eA+1], x1A2 = xr1[eA+2], x1A3 = xr1[eA+3];
    float x1B0 = xr1[eB], x1B1 = xr1[eB+1], x1B2 = xr1[eB+2], x1B3 = xr1[eB+3];
    if (pad && lane == 0) {                             // dup-chunk kill
        x0B0 = x0B1 = x0B2 = x0B3 = 0.f;
        x1B0 = x1B1 = x1B2 = x1B3 = 0.f;
    }

    // Scalar leftovers: leading [0,pad) + tail [pad+4CH,513) incl. bias 512
    const int nS = pad ? 5 : 1;
    int se = -1;
    if (lane < nS) se = (lane < pad) ? lane : (pad + 4 * CH + (lane - pad));
    float xs0 = 0.f, xs1 = 0.f, Es0 = 0.f, Es1 = 0.f, ls_mu = 0.f, ls_sg = 0.f;
    if (se >= 0) {
        xs0 = (se < 512) ? xr0[se] : 1.0f;
        xs1 = (se < 512) ? xr1[se] : 1.0f;
        Es0 = E[eb0 + se];
        Es1 = E[eb1 + se];
        uint32_t Ps = SM[cb + se];
        ls_mu = bf_mu(Ps); ls_sg = bf_sg(Ps);
    }

    // W = mu + sigma*E per element; acc_k = sum x_k * W_k
    float sgx, mux, acc0, acc1;
#define TERM(P, Ev0, Ev1, X0, X1)                                   \
    sgx = bf_sg(P); mux = bf_mu(P);                                 \
    acc0 = fmaf(X0, fmaf(sgx, Ev0, mux), acc0);                     \
    acc1 = fmaf(X1, fmaf(sgx, Ev1, mux), acc1);

    acc0 = 0.f; acc1 = 0.f;
    TERM(Pa.x, E0a.x, E1a.x, x0A0, x1A0)
    TERM(Pa.y, E0a.y, E1a.y, x0A1, x1A1)
    TERM(Pa.z, E0a.z, E1a.z, x0A2, x1A2)
    TERM(Pa.w, E0a.w, E1a.w, x0A3, x1A3)
    TERM(Pb.x, E0b.x, E1b.x, x0B0, x1B0)
    TERM(Pb.y, E0b.y, E1b.y, x0B1, x1B1)
    TERM(Pb.z, E0b.z, E1b.z, x0B2, x1B2)
    TERM(Pb.w, E0b.w, E1b.w, x0B3, x1B3)
    acc0 = fmaf(xs0, fmaf(ls_sg, Es0, ls_mu), acc0);   // leftovers (0 on idle)
    acc1 = fmaf(xs1, fmaf(ls_sg, Es1, ls_mu), acc1);
#undef TERM

    // Merged reduction: pairing stage then 5 butterflies.
    float keep = (lane & 1) ? acc1 : acc0;
    float send = (lane & 1) ? acc0 : acc1;
    float v = keep + __shfl_xor(send, 1, 64);
#pragma unroll
    for (int off = 2; off <= 32; off <<= 1)
        v += __shfl_xor(v, off, 64);

    // even lane 0 -> row m0, odd lane 1 -> row m0+1
    if (lane < 2) out[row0 + (size_t)lane * 512] = v;
}

extern "C" void kernel_launch(void* const* d_in, const int* in_sizes, int n_in,
                              void* d_out, int out_size, void* d_ws, size_t ws_size,
                              hipStream_t stream) {
    const float* x   = (const float*)d_in[0];
    const float* mu  = (const float*)d_in[1];
    const float* var = (const float*)d_in[2];
    const float* E   = (const float*)d_in[3];
    float* out = (float*)d_out;

    uint32_t* SM = (uint32_t*)d_ws;   // 1.05 MB of the ~1 GB workspace
    pack_sm_kernel<<<(SM_ELEMS + 255) / 256, 256, 0, stream>>>(var, mu, SM, SM_ELEMS);
    bnn_kernel<<<16384, 256, 0, stream>>>(x, SM, E, out);
}

// Round 10
// 49.612 us; speedup vs baseline: 2.4653x; 1.0295x over previous
//
#include <hip/hip_runtime.h>
#include <math.h>
#include <stdint.h>

// Geometry (fixed by the reference)
#define Rdim 513                   // IN_DIM + 1 bias row
#define SM_ELEMS (512 * Rdim)      // 262656 packed (sigma,mu) pairs

typedef float v4f  __attribute__((ext_vector_type(4)));
typedef uint32_t v4u __attribute__((ext_vector_type(4)));

// round-to-nearest-even fp32 -> bf16 (low 16 bits)
__device__ __forceinline__ uint32_t rne_bf16(float x) {
    uint32_t u = __float_as_uint(x);
    return (u + 0x7FFFu + ((u >> 16) & 1u)) >> 16;
}

// SM[c,r] = (bf16(mu) << 16) | bf16(sqrt(var))
__global__ __launch_bounds__(256) void pack_sm_kernel(const float* __restrict__ var,
                                                      const float* __restrict__ mu,
                                                      uint32_t* __restrict__ sm, int n) {
    int i = blockIdx.x * 256 + threadIdx.x;
    if (i < n) {
        uint32_t sb = rne_bf16(sqrtf(var[i]));
        uint32_t mb = rne_bf16(mu[i]);
        sm[i] = (mb << 16) | sb;
    }
}

__device__ __forceinline__ float bf_mu(uint32_t u) { return __uint_as_float(u & 0xFFFF0000u); }
__device__ __forceinline__ float bf_sg(uint32_t u) { return __uint_as_float(u << 16); }

// ONE wave = FOUR rows (m0..m0+3, c): SM row c loaded ONCE for four E rows.
// Block b (8192 total): mg=b>>7 (m0=4*mg), cg=b&127; wave w: c=cg*4+w.
//  - pad=(4-c%4)&3 (m*512 == 0 mod 4) -> all E/SM dwordx4 16B-aligned.
//  - Merged reduction: 2 pairing stages (xor 1, xor 2) + butterflies
//    4,8,16,32 -> lane L<4 holds the full sum of row m0+L. 6 shuffles/4 rows.
__global__ __launch_bounds__(256) void bnn_kernel(const float* __restrict__ x,
                                                  const uint32_t* __restrict__ SM,
                                                  const float* __restrict__ E,
                                                  float* __restrict__ out) {
    const int lane = threadIdx.x & 63;
    const int w    = threadIdx.x >> 6;                 // 0..3
    const int b    = blockIdx.x;                       // 0..8191
    const int mg   = b >> 7;                           // 0..63
    const int cg   = b & 127;                          // 0..127
    const int c    = cg * 4 + w;
    const int m0   = mg * 4;

    const int q    = c & 3;
    const int pad  = (4 - q) & 3;
    const int CH   = pad ? 127 : 128;                  // aligned 16B chunks
    const int eA   = pad + 4 * lane;
    const int eB   = pad + 4 * (CH - 64 + lane);

    const size_t row0 = (size_t)m0 * 512 + c;
    const size_t MS   = (size_t)512 * Rdim;            // E stride per m
    const size_t eb0  = row0 * (size_t)Rdim;
    const size_t cb   = (size_t)c * (size_t)Rdim;      // SM row
    const float* __restrict__ xr0 = x + m0 * 512;

    // ---- issue all vector loads upfront ----
    const v4u Pa  = *(const v4u*)(SM + cb + eA);
    const v4u Pb  = *(const v4u*)(SM + cb + eB);
    const v4f E0a = *(const v4f*)(E + eb0 +          eA);
    const v4f E0b = *(const v4f*)(E + eb0 +          eB);
    const v4f E1a = *(const v4f*)(E + eb0 + MS     + eA);
    const v4f E1b = *(const v4f*)(E + eb0 + MS     + eB);
    const v4f E2a = *(const v4f*)(E + eb0 + MS * 2 + eA);
    const v4f E2b = *(const v4f*)(E + eb0 + MS * 2 + eB);
    const v4f E3a = *(const v4f*)(E + eb0 + MS * 3 + eA);
    const v4f E3b = *(const v4f*)(E + eb0 + MS * 3 + eB);

    // x windows (L1-resident; shared across the block's 4 waves)
    float xA[4][4], xB[4][4];
#pragma unroll
    for (int k = 0; k < 4; ++k) {
        const float* xr = xr0 + k * 512;
        xA[k][0] = xr[eA];     xA[k][1] = xr[eA + 1];
        xA[k][2] = xr[eA + 2]; xA[k][3] = xr[eA + 3];
        xB[k][0] = xr[eB];     xB[k][1] = xr[eB + 1];
        xB[k][2] = xr[eB + 2]; xB[k][3] = xr[eB + 3];
        if (pad && lane == 0) {                         // dup-chunk kill
            xB[k][0] = xB[k][1] = xB[k][2] = xB[k][3] = 0.f;
        }
    }

    // Scalar leftovers: leading [0,pad) + tail [pad+4CH,513) incl. bias 512
    const int nS = pad ? 5 : 1;
    int se = -1;
    if (lane < nS) se = (lane < pad) ? lane : (pad + 4 * CH + (lane - pad));
    float xs[4] = {0.f, 0.f, 0.f, 0.f}, Es[4] = {0.f, 0.f, 0.f, 0.f};
    float ls_mu = 0.f, ls_sg = 0.f;
    if (se >= 0) {
        uint32_t Ps = SM[cb + se];
        ls_mu = bf_mu(Ps); ls_sg = bf_sg(Ps);
#pragma unroll
        for (int k = 0; k < 4; ++k) {
            xs[k] = (se < 512) ? xr0[k * 512 + se] : 1.0f;
            Es[k] = E[eb0 + (size_t)k * MS + se];
        }
    }

    // acc_k = sum over window of x_k * (mu + sigma*E_k)
    float acc0 = 0.f, acc1 = 0.f, acc2 = 0.f, acc3 = 0.f;
    float sgx, mux;
#define TERM(P, i, F)                                               \
    sgx = bf_sg(P); mux = bf_mu(P);                                 \
    acc0 = fmaf(F[0][i], fmaf(sgx, E0##i[i] , mux), acc0);

    // (macro got unwieldy; write the 8 steps explicitly)
#undef TERM
#define STEP(P, e0, e1, e2, e3, X, i)                               \
    sgx = bf_sg(P); mux = bf_mu(P);                                 \
    acc0 = fmaf(X[0][i], fmaf(sgx, e0, mux), acc0);                 \
    acc1 = fmaf(X[1][i], fmaf(sgx, e1, mux), acc1);                 \
    acc2 = fmaf(X[2][i], fmaf(sgx, e2, mux), acc2);                 \
    acc3 = fmaf(X[3][i], fmaf(sgx, e3, mux), acc3);

    STEP(Pa.x, E0a.x, E1a.x, E2a.x, E3a.x, xA, 0)
    STEP(Pa.y, E0a.y, E1a.y, E2a.y, E3a.y, xA, 1)
    STEP(Pa.z, E0a.z, E1a.z, E2a.z, E3a.z, xA, 2)
    STEP(Pa.w, E0a.w, E1a.w, E2a.w, E3a.w, xA, 3)
    STEP(Pb.x, E0b.x, E1b.x, E2b.x, E3b.x, xB, 0)
    STEP(Pb.y, E0b.y, E1b.y, E2b.y, E3b.y, xB, 1)
    STEP(Pb.z, E0b.z, E1b.z, E2b.z, E3b.z, xB, 2)
    STEP(Pb.w, E0b.w, E1b.w, E2b.w, E3b.w, xB, 3)
#undef STEP
    acc0 = fmaf(xs[0], fmaf(ls_sg, Es[0], ls_mu), acc0);  // leftovers
    acc1 = fmaf(xs[1], fmaf(ls_sg, Es[1], ls_mu), acc1);
    acc2 = fmaf(xs[2], fmaf(ls_sg, Es[2], ls_mu), acc2);
    acc3 = fmaf(xs[3], fmaf(ls_sg, Es[3], ls_mu), acc3);

    // Merged reduction: 2 pairing stages + 4 butterflies.
    // Stage 1 (xor 1): even lanes keep rows {0,2}, odd keep {1,3}.
    float k01 = (lane & 1) ? acc1 : acc0;
    float s01 = (lane & 1) ? acc0 : acc1;
    float v01 = k01 + __shfl_xor(s01, 1, 64);
    float k23 = (lane & 1) ? acc3 : acc2;
    float s23 = (lane & 1) ? acc2 : acc3;
    float v23 = k23 + __shfl_xor(s23, 1, 64);
    // Stage 2 (xor 2): bit1 selects {0,1} vs {2,3}.
    float kq = (lane & 2) ? v23 : v01;
    float sq = (lane & 2) ? v01 : v23;
    float v  = kq + __shfl_xor(sq, 2, 64);
    // Full butterflies: lane L ends with total of row m0 + (L&3).
#pragma unroll
    for (int off = 4; off <= 32; off <<= 1)
        v += __shfl_xor(v, off, 64);

    if (lane < 4) out[row0 + (size_t)lane * 512] = v;
}

extern "C" void kernel_launch(void* const* d_in, const int* in_sizes, int n_in,
                              void* d_out, int out_size, void* d_ws, size_t ws_size,
                              hipStream_t stream) {
    const float* x   = (const float*)d_in[0];
    const float* mu  = (const float*)d_in[1];
    const float* var = (const float*)d_in[2];
    const float* E   = (const float*)d_in[3];
    float* out = (float*)d_out;

    uint32_t* SM = (uint32_t*)d_ws;   // 1.05 MB of the ~1 GB workspace
    pack_sm_kernel<<<(SM_ELEMS + 255) / 256, 256, 0, stream>>>(var, mu, SM, SM_ELEMS);
    bnn_kernel<<<8192, 256, 0, stream>>>(x, SM, E, out);
}

// Round 11
// 44.557 us; speedup vs baseline: 2.7450x; 1.1135x over previous
//
#include <hip/hip_runtime.h>
#include <math.h>
#include <stdint.h>

// Geometry (fixed by the reference)
#define Rdim 513                   // IN_DIM + 1 bias row

typedef float v4f __attribute__((ext_vector_type(4)));

// SINGLE-KERNEL variant of the proven R10 structure (49.6us):
//   ONE wave = FOUR rows (m0..m0+3, c); mu/var row c loaded ONCE (fp32,
//   4KB per 4 rows), sigma = sqrt(var) computed in registers (VALU ~5% busy).
//   No pack pre-kernel -> one dispatch per replay instead of two.
// Block b (8192): mg=b>>7 (m0=4*mg), cg=b&127; wave w: c=cg*4+w.
//  - pad=(4-c%4)&3 (m*512 == 0 mod 4) -> all E/mu/var dwordx4 16B-aligned
//    (row element base = row*513 == c mod 4; pad cancels it).
//  - Merged reduction: 2 pairing stages (xor 1, xor 2) + butterflies
//    4,8,16,32 -> lane L<4 holds the full sum of row m0+L. 6 shuffles/4 rows.
__global__ __launch_bounds__(256) void bnn_kernel(const float* __restrict__ x,
                                                  const float* __restrict__ mu,
                                                  const float* __restrict__ var,
                                                  const float* __restrict__ E,
                                                  float* __restrict__ out) {
    const int lane = threadIdx.x & 63;
    const int w    = threadIdx.x >> 6;                 // 0..3
    const int b    = blockIdx.x;                       // 0..8191
    const int mg   = b >> 7;                           // 0..63
    const int cg   = b & 127;                          // 0..127
    const int c    = cg * 4 + w;
    const int m0   = mg * 4;

    const int q    = c & 3;
    const int pad  = (4 - q) & 3;
    const int CH   = pad ? 127 : 128;                  // aligned 16B chunks
    const int eA   = pad + 4 * lane;
    const int eB   = pad + 4 * (CH - 64 + lane);

    const size_t row0 = (size_t)m0 * 512 + c;
    const size_t MS   = (size_t)512 * Rdim;            // E stride per m
    const size_t eb0  = row0 * (size_t)Rdim;
    const size_t cb   = (size_t)c * (size_t)Rdim;      // mu/var row
    const float* __restrict__ xr0 = x + m0 * 512;

    // ---- issue all vector loads upfront ----
    const v4f Ma  = *(const v4f*)(mu  + cb + eA);
    const v4f Mb  = *(const v4f*)(mu  + cb + eB);
    const v4f Va  = *(const v4f*)(var + cb + eA);
    const v4f Vb  = *(const v4f*)(var + cb + eB);
    const v4f E0a = *(const v4f*)(E + eb0 +          eA);
    const v4f E0b = *(const v4f*)(E + eb0 +          eB);
    const v4f E1a = *(const v4f*)(E + eb0 + MS     + eA);
    const v4f E1b = *(const v4f*)(E + eb0 + MS     + eB);
    const v4f E2a = *(const v4f*)(E + eb0 + MS * 2 + eA);
    const v4f E2b = *(const v4f*)(E + eb0 + MS * 2 + eB);
    const v4f E3a = *(const v4f*)(E + eb0 + MS * 3 + eA);
    const v4f E3b = *(const v4f*)(E + eb0 + MS * 3 + eB);

    // sigma in registers
    v4f Sa, Sb;
    Sa.x = sqrtf(Va.x); Sa.y = sqrtf(Va.y); Sa.z = sqrtf(Va.z); Sa.w = sqrtf(Va.w);
    Sb.x = sqrtf(Vb.x); Sb.y = sqrtf(Vb.y); Sb.z = sqrtf(Vb.z); Sb.w = sqrtf(Vb.w);

    // x windows (L1-resident; shared across the block's 4 waves)
    float xA[4][4], xB[4][4];
#pragma unroll
    for (int k = 0; k < 4; ++k) {
        const float* xr = xr0 + k * 512;
        xA[k][0] = xr[eA];     xA[k][1] = xr[eA + 1];
        xA[k][2] = xr[eA + 2]; xA[k][3] = xr[eA + 3];
        xB[k][0] = xr[eB];     xB[k][1] = xr[eB + 1];
        xB[k][2] = xr[eB + 2]; xB[k][3] = xr[eB + 3];
        if (pad && lane == 0) {                         // dup-chunk kill
            xB[k][0] = xB[k][1] = xB[k][2] = xB[k][3] = 0.f;
        }
    }

    // Scalar leftovers: leading [0,pad) + tail [pad+4CH,513) incl. bias 512
    const int nS = pad ? 5 : 1;
    int se = -1;
    if (lane < nS) se = (lane < pad) ? lane : (pad + 4 * CH + (lane - pad));
    float xs[4] = {0.f, 0.f, 0.f, 0.f}, Es[4] = {0.f, 0.f, 0.f, 0.f};
    float ls_mu = 0.f, ls_sg = 0.f;
    if (se >= 0) {
        ls_mu = mu[cb + se];
        ls_sg = sqrtf(var[cb + se]);
#pragma unroll
        for (int k = 0; k < 4; ++k) {
            xs[k] = (se < 512) ? xr0[k * 512 + se] : 1.0f;
            Es[k] = E[eb0 + (size_t)k * MS + se];
        }
    }

    // acc_k = sum over window of x_k * (mu + sigma*E_k)
    float acc0 = 0.f, acc1 = 0.f, acc2 = 0.f, acc3 = 0.f;
#define STEP(sg_, mu_, e0, e1, e2, e3, X, i)                        \
    acc0 = fmaf(X[0][i], fmaf(sg_, e0, mu_), acc0);                 \
    acc1 = fmaf(X[1][i], fmaf(sg_, e1, mu_), acc1);                 \
    acc2 = fmaf(X[2][i], fmaf(sg_, e2, mu_), acc2);                 \
    acc3 = fmaf(X[3][i], fmaf(sg_, e3, mu_), acc3);

    STEP(Sa.x, Ma.x, E0a.x, E1a.x, E2a.x, E3a.x, xA, 0)
    STEP(Sa.y, Ma.y, E0a.y, E1a.y, E2a.y, E3a.y, xA, 1)
    STEP(Sa.z, Ma.z, E0a.z, E1a.z, E2a.z, E3a.z, xA, 2)
    STEP(Sa.w, Ma.w, E0a.w, E1a.w, E2a.w, E3a.w, xA, 3)
    STEP(Sb.x, Mb.x, E0b.x, E1b.x, E2b.x, E3b.x, xB, 0)
    STEP(Sb.y, Mb.y, E0b.y, E1b.y, E2b.y, E3b.y, xB, 1)
    STEP(Sb.z, Mb.z, E0b.z, E1b.z, E2b.z, E3b.z, xB, 2)
    STEP(Sb.w, Mb.w, E0b.w, E1b.w, E2b.w, E3b.w, xB, 3)
#undef STEP
    acc0 = fmaf(xs[0], fmaf(ls_sg, Es[0], ls_mu), acc0);  // leftovers
    acc1 = fmaf(xs[1], fmaf(ls_sg, Es[1], ls_mu), acc1);
    acc2 = fmaf(xs[2], fmaf(ls_sg, Es[2], ls_mu), acc2);
    acc3 = fmaf(xs[3], fmaf(ls_sg, Es[3], ls_mu), acc3);

    // Merged reduction: 2 pairing stages + 4 butterflies.
    float k01 = (lane & 1) ? acc1 : acc0;
    float s01 = (lane & 1) ? acc0 : acc1;
    float v01 = k01 + __shfl_xor(s01, 1, 64);
    float k23 = (lane & 1) ? acc3 : acc2;
    float s23 = (lane & 1) ? acc2 : acc3;
    float v23 = k23 + __shfl_xor(s23, 1, 64);
    float kq = (lane & 2) ? v23 : v01;
    float sq = (lane & 2) ? v01 : v23;
    float v  = kq + __shfl_xor(sq, 2, 64);
#pragma unroll
    for (int off = 4; off <= 32; off <<= 1)
        v += __shfl_xor(v, off, 64);

    // lane L < 4 holds total of row m0 + L
    if (lane < 4) out[row0 + (size_t)lane * 512] = v;
}

extern "C" void kernel_launch(void* const* d_in, const int* in_sizes, int n_in,
                              void* d_out, int out_size, void* d_ws, size_t ws_size,
                              hipStream_t stream) {
    const float* x   = (const float*)d_in[0];
    const float* mu  = (const float*)d_in[1];
    const float* var = (const float*)d_in[2];
    const float* E   = (const float*)d_in[3];
    float* out = (float*)d_out;

    bnn_kernel<<<8192, 256, 0, stream>>>(x, mu, var, E, out);
}